// Round 13
// baseline (981.343 us; speedup 1.0000x reference)
//
#include <hip/hip_runtime.h>
#include <hip/hip_bf16.h>
#include <stdint.h>

typedef float f32x4 __attribute__((ext_vector_type(4)));
typedef short s16x8 __attribute__((ext_vector_type(8)));
typedef int i32x8 __attribute__((ext_vector_type(8)));
typedef unsigned int u32x4 __attribute__((ext_vector_type(4)));
typedef unsigned long long u64;

#define INV_SCALE (1.0f / 1024.0f)  // W pre-scaled x64, h x16
#define SCALE_ONE 0x7F7F7F7F        // E8M0 1.0 in every byte
#define LOG2E 1.4426950408889634f

__device__ __forceinline__ float sigm(float x) {
  return __builtin_amdgcn_rcpf(1.f + __builtin_amdgcn_exp2f(-LOG2E * x));
}
__device__ __forceinline__ ushort f2bf(float f) {
  union { float f; uint32_t u; } v; v.f = f;
  return (ushort)((v.u + 0x7FFFu + ((v.u >> 16) & 1)) >> 16);
}
__device__ __forceinline__ float bf2f(ushort b) {
  union { uint32_t u; float f; } v; v.u = ((uint32_t)b) << 16; return v.f;
}

// ---------------- prep: permutes + converts (emb handled in gemm_xp now) ----------------
__global__ __launch_bounds__(256) void prep_kernel(
    const int* __restrict__ x,
    const float* __restrict__ Wih0, const float* __restrict__ Wih1,
    const float* __restrict__ bih0, const float* __restrict__ bhh0,
    const float* __restrict__ bih1, const float* __restrict__ bhh1,
    int* __restrict__ idx_ws,
    ushort* __restrict__ W0p, unsigned char* __restrict__ W1p8,
    float* __restrict__ b0p, float* __restrict__ b1p,
    unsigned int* __restrict__ done0)
{
  const int stride = gridDim.x * blockDim.x;
  const int gid = blockIdx.x * blockDim.x + threadIdx.x;
  // idx_ws[t*128+b] = x[b*512+t]
  for (int i = gid; i < 65536; i += stride) idx_ws[i] = x[(i & 127) * 512 + (i >> 7)];
  // W0p[j][k] = Wih0[(j&3)*256 + (j>>2)][k]   (j = hid*4 + gate) bf16 (layer-0 xp GEMM)
  for (int i = gid; i < 1024 * 128; i += stride) {
    int j = i >> 7, k = i & 127;
    int p = ((j & 3) << 8) | (j >> 2);
    W0p[i] = f2bf(Wih0[p * 128 + k]);
  }
  // W1p8: RAW layout (row = gate*256+hid), fp8 e4m3 x64 (consumer chunk GEMM, R8-proven)
  for (int i = gid; i < 131072; i += stride) {
    int q = __builtin_amdgcn_cvt_pk_fp8_f32(Wih1[2 * i] * 64.f, Wih1[2 * i + 1] * 64.f, 0, false);
    ((ushort*)W1p8)[i] = (ushort)(q & 0xFFFF);
  }
  for (int i = gid; i < 1024; i += stride) {
    int p = ((i & 3) << 8) | (i >> 2);
    b0p[i] = bih0[p] + bhh0[p];   // gate-interleaved (layer 0 xp GEMM)
    b1p[i] = bih1[p] + bhh1[p];   // gate-interleaved (consumer epilogue)
  }
  for (int i = gid; i < 128; i += stride) done0[i] = 0;  // reset chunk flags each launch
}

// ---------------- wide GEMM for xp0: xp[m][j] = emb[idx[m],:] @ W0p[j,:]^T + b0p[j] ----------------
// A path reads emb as f32 and converts to bf16 during staging (no emb_bf pass).
__global__ __launch_bounds__(256) void gemm_xp0(
    const float* __restrict__ embf, const int* __restrict__ idx,
    const ushort* __restrict__ B, const float* __restrict__ bias,
    ushort* __restrict__ out)
{
  __shared__ ushort Al[128 * 72];
  __shared__ ushort Bl[128 * 72];
  const int tid = threadIdx.x;
  const int l = tid & 63, w = tid >> 6;
  const int wm = w >> 1, wn = w & 1;
  const int lr = l & 15, lg = l >> 4;
  const int m0 = blockIdx.x * 128, n0 = blockIdx.y * 128;

  f32x4 acc[4][4];
#pragma unroll
  for (int a = 0; a < 4; ++a)
#pragma unroll
    for (int b = 0; b < 4; ++b) acc[a][b] = (f32x4)0.f;

  const int srow = tid >> 1, sseg = tid & 1;
  for (int kk = 0; kk < 2; ++kk) {
    const int k0 = kk * 64;
    const size_t arow = (size_t)idx[m0 + srow];
    // A: 32 f32 -> 32 bf16 in-register
    const float* sa = embf + arow * 128 + k0 + sseg * 32;
    uint4 pk0, pk1;
    {
      uint tmp[8];
#pragma unroll
      for (int j = 0; j < 8; ++j) {
        const f32x4 v = *(const f32x4*)(sa + j * 4);
        tmp[j] = (uint)f2bf(v[0]) | ((uint)f2bf(v[1]) << 16);
        tmp[j] |= 0;  // keep pairing explicit
        uint hi = (uint)f2bf(v[2]) | ((uint)f2bf(v[3]) << 16);
        if (j < 4) { ((uint*)&pk0)[j] = 0; }
        // build two uint4s: each f32x4 -> 2 dwords
        uint lo = tmp[j];
        if (j == 0) { pk0.x = lo; pk0.y = hi; }
        else if (j == 1) { pk0.z = lo; pk0.w = hi; }
        else if (j == 2) { pk1.x = lo; pk1.y = hi; }
        else if (j == 3) { pk1.z = lo; pk1.w = hi; }
        else {
          // j 4..7 -> second 32B half
          uint4* da2 = (uint4*)(Al + srow * 72 + sseg * 32 + 16);
          if (j == 4) { ((uint*)da2)[0] = lo; ((uint*)da2)[1] = hi; }
          else if (j == 5) { ((uint*)da2)[2] = lo; ((uint*)da2)[3] = hi; }
          else if (j == 6) { ((uint*)(da2 + 1))[0] = lo; ((uint*)(da2 + 1))[1] = hi; }
          else { ((uint*)(da2 + 1))[2] = lo; ((uint*)(da2 + 1))[3] = hi; }
        }
      }
      uint4* da = (uint4*)(Al + srow * 72 + sseg * 32);
      da[0] = pk0; da[1] = pk1;
    }
    const uint4* sb = (const uint4*)(B + (size_t)(n0 + srow) * 128 + k0 + sseg * 32);
    uint4* db = (uint4*)(Bl + srow * 72 + sseg * 32);
    db[0] = sb[0]; db[1] = sb[1]; db[2] = sb[2]; db[3] = sb[3];
    __syncthreads();
#pragma unroll
    for (int ks = 0; ks < 2; ++ks) {
      s16x8 av[4], bv[4];
#pragma unroll
      for (int mt = 0; mt < 4; ++mt)
        av[mt] = *(const s16x8*)(Al + (wm * 64 + mt * 16 + lr) * 72 + ks * 32 + lg * 8);
#pragma unroll
      for (int nt = 0; nt < 4; ++nt)
        bv[nt] = *(const s16x8*)(Bl + (wn * 64 + nt * 16 + lr) * 72 + ks * 32 + lg * 8);
#pragma unroll
      for (int mt = 0; mt < 4; ++mt)
#pragma unroll
        for (int nt = 0; nt < 4; ++nt)
          acc[mt][nt] = __builtin_amdgcn_mfma_f32_16x16x32_bf16(av[mt], bv[nt], acc[mt][nt], 0, 0, 0);
    }
    __syncthreads();
  }

#pragma unroll
  for (int nt = 0; nt < 4; ++nt) {
    const int colg = n0 + wn * 64 + nt * 16 + lr;
    const float bv = bias[colg];
#pragma unroll
    for (int mt = 0; mt < 4; ++mt) {
#pragma unroll
      for (int i = 0; i < 4; ++i) {
        const int rowg = m0 + wm * 64 + mt * 16 + 4 * lg + i;
        // non-temporal: xp0 is streamed once by the producers; keep it out of L2
        __builtin_nontemporal_store(f2bf(acc[mt][nt][i] + bv), &out[(size_t)rowg * 1024 + colg]);
      }
    }
  }
}

// ---------------- mega: layer-0 scan (WG 0-127) || layer-1 scan (WG 128-255) ----------------
// R12 structure + u64 publish/stage atomics (halved coherence-point transactions).
__global__ __launch_bounds__(1024) void mega_scan(
    const ushort* __restrict__ xp0, const float* __restrict__ Whh0,
    const float* __restrict__ Whh1, const unsigned char* __restrict__ W1p8,
    const float* __restrict__ b1p, u64* __restrict__ hs64,
    unsigned int* __restrict__ done0, const float* __restrict__ fcw,
    const float* __restrict__ fcb, float* __restrict__ out)
{
  __shared__ __align__(16) unsigned char smem[38800];
  ushort* xpcu = (ushort*)smem;                 // [16][1024] bf16 xp chunk (both roles)
  unsigned char* h0l = smem + 32768;            // [16][272]  fp8 h0 chunk stage (consumer)
  unsigned char* hbb = smem + 37120;            // [2][320]   h ping-pong fp8
  float* hf = (float*)(smem + 37760);           // [260]      final h f32

  const int tid = threadIdx.x;
  const int l = tid & 63, w = tid >> 6;
  const int lr = l & 15, lg = l >> 4;
  const bool is0 = blockIdx.x < 128;
  const int b = is0 ? blockIdx.x : (blockIdx.x - 128);
  const float* Whh = is0 ? Whh0 : Whh1;
  const int hcol = 16 * w + lr;

  // W_hh fragments (fp8 x64): gate s, k-chunk kc; B col = 256*s + hcol, k = kc*128 + lg*32 + j
  i32x8 wf[4][2];
#pragma unroll
  for (int s = 0; s < 4; ++s) {
    const int n = 256 * s + hcol;
#pragma unroll
    for (int kc = 0; kc < 2; ++kc) {
      i32x8 r;
#pragma unroll
      for (int d = 0; d < 8; ++d) {
        const f32x4 v = *(const f32x4*)(Whh + (size_t)n * 256 + kc * 128 + lg * 32 + d * 4);
        int q = __builtin_amdgcn_cvt_pk_fp8_f32(v[0] * 64.f, v[1] * 64.f, 0, false);
        q = __builtin_amdgcn_cvt_pk_fp8_f32(v[2] * 64.f, v[3] * 64.f, q, true);
        r[d] = q;
      }
      wf[s][kc] = r;
    }
  }

  if (tid < 320) hbb[tid] = 0;  // h(-1) = 0 (buffer 0)
  float cc = 0.f;

  if (is0) {
    // ================= layer 0 producer: per-chunk LDS xp stage + u64 burst publish =================
    const int tr = tid >> 6;      // timestep-in-chunk this thread stages
    const int part = tid & 63;    // 32B segment
    __syncthreads();
    for (int c = 0; c < 32; ++c) {
      // stage chunk c's xp (16 x 1024 bf16 = 32 KB) -> LDS, non-temporal
      {
        const ushort* src = xp0 + ((size_t)((c * 16 + tr) * 128 + b)) * 1024 + part * 16;
        u32x4 a0 = __builtin_nontemporal_load((const u32x4*)src);
        u32x4 a1 = __builtin_nontemporal_load((const u32x4*)(src + 8));
        *(u32x4*)(xpcu + tr * 1024 + part * 16) = a0;
        *(u32x4*)(xpcu + tr * 1024 + part * 16 + 8) = a1;
      }
      __syncthreads();  // chunk xp ready; NT loads drained ONCE per chunk
      u64 pub[16];
#pragma unroll
      for (int ts = 0; ts < 16; ++ts) {
        const unsigned char* hr = hbb + ((ts & 1) * 320);
        unsigned char* hw = hbb + (((ts & 1) ^ 1) * 320);
        i32x8 af[2];
#pragma unroll
        for (int kc = 0; kc < 2; ++kc) {
          const uint4* p = (const uint4*)(hr + kc * 128 + lg * 32);
          uint4 lo = p[0], hi = p[1];
          i32x8 a;
          a[0] = lo.x; a[1] = lo.y; a[2] = lo.z; a[3] = lo.w;
          a[4] = hi.x; a[5] = hi.y; a[6] = hi.z; a[7] = hi.w;
          af[kc] = a;
        }
        f32x4 acc0 = (f32x4)0.f, acc1 = (f32x4)0.f, acc2 = (f32x4)0.f, acc3 = (f32x4)0.f;
#pragma unroll
        for (int kc = 0; kc < 2; ++kc) {
          acc0 = __builtin_amdgcn_mfma_scale_f32_16x16x128_f8f6f4(af[kc], wf[0][kc], acc0, 0, 0, 0, SCALE_ONE, 0, SCALE_ONE);
          acc1 = __builtin_amdgcn_mfma_scale_f32_16x16x128_f8f6f4(af[kc], wf[1][kc], acc1, 0, 0, 0, SCALE_ONE, 0, SCALE_ONE);
          acc2 = __builtin_amdgcn_mfma_scale_f32_16x16x128_f8f6f4(af[kc], wf[2][kc], acc2, 0, 0, 0, SCALE_ONE, 0, SCALE_ONE);
          acc3 = __builtin_amdgcn_mfma_scale_f32_16x16x128_f8f6f4(af[kc], wf[3][kc], acc3, 0, 0, 0, SCALE_ONE, 0, SCALE_ONE);
        }
        // xp for this step from LDS (broadcast across lg groups)
        const uint2 xpv = *(const uint2*)(xpcu + ts * 1024 + (hcol << 2));
        const uint word = (lg & 2) ? xpv.y : xpv.x;
        const uint h16 = (lg & 1) ? (word >> 16) : (word & 0xFFFFu);
        union { uint32_t u; float f; } xf; xf.u = h16 << 16;
        const float accsel = (lg & 2) ? ((lg & 1) ? acc3[0] : acc2[0])
                                      : ((lg & 1) ? acc1[0] : acc0[0]);
        const float p = accsel * INV_SCALE + xf.f;
        const float kk2 = (lg == 2) ? (2.f * LOG2E) : LOG2E;
        const float mm = (lg == 2) ? 2.f : 1.f;
        const float ex = __builtin_amdgcn_exp2f(kk2 * p);
        const float v = 1.f - mm * __builtin_amdgcn_rcpf(ex + 1.f);
        const float sf = __shfl(v, lr + 16);
        const float tg = __shfl(v, lr + 32);
        const float so = __shfl(v, lr + 48);
        cc = sf * cc + v * tg;
        const float e2 = __builtin_amdgcn_exp2f(2.f * LOG2E * cc);
        const float th = 1.f - 2.f * __builtin_amdgcn_rcpf(e2 + 1.f);
        const float h = so * th;
        int q = __builtin_amdgcn_cvt_pk_fp8_f32(h * 16.f, h * 16.f, 0, false);
        if (lg == 0) hw[hcol] = (unsigned char)(q & 0xFF);
        // pack 8 fp8 bytes (cols 16w+8i..+7) into a u64 on lanes (l&7)==0; buffer in regs
        uint v8 = (uint)(q & 0xFF);
        uint v1 = (uint)__shfl((int)v8, (int)(l ^ 1));
        uint u2b = v8 | (v1 << 8);
        uint v2 = (uint)__shfl((int)u2b, (int)(l ^ 2));
        uint u4b = u2b | (v2 << 16);
        uint hi4 = (uint)__shfl((int)u4b, (int)(l ^ 4));
        pub[ts] = (u64)u4b | ((u64)hi4 << 32);
        __syncthreads();  // vmem-free steady state
      }
      // burst-publish the chunk (one drain), then flag
      if (lg == 0 && (l & 7) == 0) {
        u64* dst = hs64 + ((size_t)b * 512 + c * 16) * 32 + 2 * w + (l >> 3);
#pragma unroll
        for (int ts = 0; ts < 16; ++ts)
          __hip_atomic_store(dst + (size_t)ts * 32, pub[ts],
                             __ATOMIC_RELAXED, __HIP_MEMORY_SCOPE_AGENT);
      }
      __syncthreads();  // each wave drains its own publish stores before the flag
      if (tid == 0)
        __hip_atomic_store(done0 + b, (unsigned)(c + 1),
                           __ATOMIC_RELAXED, __HIP_MEMORY_SCOPE_AGENT);
    }
  } else {
    // ================= layer 1 consumer: R8-proven fp8 chunk GEMM + recurrence =================
    const f32x4 bias = *(const f32x4*)(b1p + (hcol << 2));
    __syncthreads();
    for (int c = 0; c < 32; ++c) {
      if (tid == 0) {
        while (__hip_atomic_load(done0 + b, __ATOMIC_RELAXED, __HIP_MEMORY_SCOPE_AGENT)
               < (unsigned)(c + 1))
          __builtin_amdgcn_s_sleep(2);
      }
      __syncthreads();
      // stage 16x256 fp8 h0 chunk -> LDS (rows padded to 272), u64 relaxed atomic loads
      if (tid < 512) {
        const int r = tid >> 5, kq = tid & 31;
        const u64 v = __hip_atomic_load(
            hs64 + ((size_t)b * 512 + (c << 4) + r) * 32 + kq,
            __ATOMIC_RELAXED, __HIP_MEMORY_SCOPE_AGENT);
        *(u64*)(h0l + r * 272 + (kq << 3)) = v;
      }
      __syncthreads();
      // chunk GEMM: A rows = 16 timesteps (lane lr), B = W_ih1 fp8 from L2
      f32x4 ga0 = (f32x4)0.f, ga1 = (f32x4)0.f, ga2 = (f32x4)0.f, ga3 = (f32x4)0.f;
#pragma unroll
      for (int kc = 0; kc < 2; ++kc) {
        const uint4* ap = (const uint4*)(h0l + lr * 272 + (kc << 7) + (lg << 5));
        uint4 alo = ap[0], ahi = ap[1];
        i32x8 a;
        a[0] = alo.x; a[1] = alo.y; a[2] = alo.z; a[3] = alo.w;
        a[4] = ahi.x; a[5] = ahi.y; a[6] = ahi.z; a[7] = ahi.w;
        const unsigned char* wb = W1p8 + (size_t)hcol * 256 + (kc << 7) + (lg << 5);
#pragma unroll
        for (int g = 0; g < 4; ++g) {
          const uint4* bp = (const uint4*)(wb + (size_t)g * 65536);
          uint4 blo = bp[0], bhi = bp[1];
          i32x8 bv;
          bv[0] = blo.x; bv[1] = blo.y; bv[2] = blo.z; bv[3] = blo.w;
          bv[4] = bhi.x; bv[5] = bhi.y; bv[6] = bhi.z; bv[7] = bhi.w;
          if (g == 0) ga0 = __builtin_amdgcn_mfma_scale_f32_16x16x128_f8f6f4(a, bv, ga0, 0, 0, 0, SCALE_ONE, 0, SCALE_ONE);
          if (g == 1) ga1 = __builtin_amdgcn_mfma_scale_f32_16x16x128_f8f6f4(a, bv, ga1, 0, 0, 0, SCALE_ONE, 0, SCALE_ONE);
          if (g == 2) ga2 = __builtin_amdgcn_mfma_scale_f32_16x16x128_f8f6f4(a, bv, ga2, 0, 0, 0, SCALE_ONE, 0, SCALE_ONE);
          if (g == 3) ga3 = __builtin_amdgcn_mfma_scale_f32_16x16x128_f8f6f4(a, bv, ga3, 0, 0, 0, SCALE_ONE, 0, SCALE_ONE);
        }
      }
      // xp chunk -> LDS bf16, bias folded; C row = 4*lg + i (timestep), gate-interleaved cols
#pragma unroll
      for (int i = 0; i < 4; ++i) {
        const int row = (lg << 2) + i;
        union { uint2 u; ushort s[4]; } pk;
        pk.s[0] = f2bf(ga0[i] * INV_SCALE + bias[0]);
        pk.s[1] = f2bf(ga1[i] * INV_SCALE + bias[1]);
        pk.s[2] = f2bf(ga2[i] * INV_SCALE + bias[2]);
        pk.s[3] = f2bf(ga3[i] * INV_SCALE + bias[3]);
        *(uint2*)(xpcu + row * 1024 + (hcol << 2)) = pk.u;
      }
      __syncthreads();
      // 16 recurrent steps (R7-verified structure, xp from LDS gate-interleaved)
      for (int ts = 0; ts < 16; ++ts) {
        const int t = (c << 4) + ts;
        const unsigned char* hr = hbb + ((t & 1) * 320);
        unsigned char* hw = hbb + (((t & 1) ^ 1) * 320);
        i32x8 af[2];
#pragma unroll
        for (int kc = 0; kc < 2; ++kc) {
          const uint4* p = (const uint4*)(hr + kc * 128 + lg * 32);
          uint4 lo = p[0], hi = p[1];
          i32x8 a;
          a[0] = lo.x; a[1] = lo.y; a[2] = lo.z; a[3] = lo.w;
          a[4] = hi.x; a[5] = hi.y; a[6] = hi.z; a[7] = hi.w;
          af[kc] = a;
        }
        f32x4 acc0 = (f32x4)0.f, acc1 = (f32x4)0.f, acc2 = (f32x4)0.f, acc3 = (f32x4)0.f;
#pragma unroll
        for (int kc = 0; kc < 2; ++kc) {
          acc0 = __builtin_amdgcn_mfma_scale_f32_16x16x128_f8f6f4(af[kc], wf[0][kc], acc0, 0, 0, 0, SCALE_ONE, 0, SCALE_ONE);
          acc1 = __builtin_amdgcn_mfma_scale_f32_16x16x128_f8f6f4(af[kc], wf[1][kc], acc1, 0, 0, 0, SCALE_ONE, 0, SCALE_ONE);
          acc2 = __builtin_amdgcn_mfma_scale_f32_16x16x128_f8f6f4(af[kc], wf[2][kc], acc2, 0, 0, 0, SCALE_ONE, 0, SCALE_ONE);
          acc3 = __builtin_amdgcn_mfma_scale_f32_16x16x128_f8f6f4(af[kc], wf[3][kc], acc3, 0, 0, 0, SCALE_ONE, 0, SCALE_ONE);
        }
        const float xv = bf2f(xpcu[ts * 1024 + (hcol << 2) + lg]);
        const float accsel = (lg & 2) ? ((lg & 1) ? acc3[0] : acc2[0])
                                      : ((lg & 1) ? acc1[0] : acc0[0]);
        const float p = accsel * INV_SCALE + xv;
        const float kk2 = (lg == 2) ? (2.f * LOG2E) : LOG2E;
        const float mm = (lg == 2) ? 2.f : 1.f;
        const float ex = __builtin_amdgcn_exp2f(kk2 * p);
        const float v = 1.f - mm * __builtin_amdgcn_rcpf(ex + 1.f);
        const float sf = __shfl(v, lr + 16);
        const float tg = __shfl(v, lr + 32);
        const float so = __shfl(v, lr + 48);
        cc = sf * cc + v * tg;
        const float e2 = __builtin_amdgcn_exp2f(2.f * LOG2E * cc);
        const float th = 1.f - 2.f * __builtin_amdgcn_rcpf(e2 + 1.f);
        const float h = so * th;
        if (lg == 0) {
          int q = __builtin_amdgcn_cvt_pk_fp8_f32(h * 16.f, h * 16.f, 0, false);
          hw[hcol] = (unsigned char)(q & 0xFF);
          if (t == 511) hf[hcol] = h;
        }
        __syncthreads();
      }
    }
    // fc epilogue
    if (w == 0) {
      float s = 0.f;
#pragma unroll
      for (int j = 0; j < 4; ++j) {
        const int k = j * 64 + l;
        s += hf[k] * fcw[k];
      }
      s += __shfl_xor(s, 1);
      s += __shfl_xor(s, 2);
      s += __shfl_xor(s, 4);
      s += __shfl_xor(s, 8);
      s += __shfl_xor(s, 16);
      s += __shfl_xor(s, 32);
      if (l == 0) out[b] = sigm(s + fcb[0]);
    }
  }
}

// ---------------- launch ----------------
extern "C" void kernel_launch(void* const* d_in, const int* in_sizes, int n_in,
                              void* d_out, int out_size, void* d_ws, size_t ws_size,
                              hipStream_t stream)
{
  const int*   x    = (const int*)d_in[0];
  const float* emb  = (const float*)d_in[1];
  const float* fcw  = (const float*)d_in[2];
  const float* fcb  = (const float*)d_in[3];
  const float* Wih0 = (const float*)d_in[4];
  const float* Whh0 = (const float*)d_in[5];
  const float* bih0 = (const float*)d_in[6];
  const float* bhh0 = (const float*)d_in[7];
  const float* Wih1 = (const float*)d_in[8];
  const float* Whh1 = (const float*)d_in[9];
  const float* bih1 = (const float*)d_in[10];
  const float* bhh1 = (const float*)d_in[11];

  char* ws = (char*)d_ws;
  size_t off = 0;
  auto alloc = [&](size_t bytes) {
    void* p = ws + off;
    off = (off + bytes + 255) & ~(size_t)255;
    return p;
  };
  ushort*        xp_ws  = (ushort*)alloc(65536ull * 1024 * 2);
  u64*           hs64   = (u64*)alloc(128ull * 512 * 32 * 8);
  ushort*        W0p    = (ushort*)alloc(1024ull * 128 * 2);
  unsigned char* W1p8   = (unsigned char*)alloc(1024ull * 256);
  float*         b0p    = (float*)alloc(1024 * 4);
  float*         b1p    = (float*)alloc(1024 * 4);
  int*           idx_ws = (int*)alloc(65536 * 4);
  unsigned int*  done0  = (unsigned int*)alloc(128 * 4);

  prep_kernel<<<256, 256, 0, stream>>>(x, Wih0, Wih1, bih0, bhh0, bih1, bhh1,
                                       idx_ws, W0p, W1p8, b0p, b1p, done0);
  gemm_xp0<<<dim3(512, 8), 256, 0, stream>>>(emb, idx_ws, W0p, b0p, xp_ws);
  mega_scan<<<256, 1024, 0, stream>>>(xp_ws, Whh0, Whh1, W1p8, b1p, hs64, done0,
                                      fcw, fcb, (float*)d_out);
}

// Round 14
// 820.679 us; speedup vs baseline: 1.1958x; 1.1958x over previous
//
#include <hip/hip_runtime.h>
#include <hip/hip_bf16.h>
#include <stdint.h>

typedef float f32x4 __attribute__((ext_vector_type(4)));
typedef short s16x8 __attribute__((ext_vector_type(8)));
typedef int i32x8 __attribute__((ext_vector_type(8)));
typedef unsigned long long u64;

#define INV_SCALE (1.0f / 1024.0f)  // W pre-scaled x64, h x16
#define SCALE_ONE 0x7F7F7F7F        // E8M0 1.0 in every byte
#define LOG2E 1.4426950408889634f

__device__ __forceinline__ float sigm(float x) {
  return __builtin_amdgcn_rcpf(1.f + __builtin_amdgcn_exp2f(-LOG2E * x));
}
__device__ __forceinline__ ushort f2bf(float f) {
  union { float f; uint32_t u; } v; v.f = f;
  return (ushort)((v.u + 0x7FFFu + ((v.u >> 16) & 1)) >> 16);
}
__device__ __forceinline__ float bf2f(ushort b) {
  union { uint32_t u; float f; } v; v.u = ((uint32_t)b) << 16; return v.f;
}

// ---------------- prep: weight permutes/converts + flag reset ----------------
__global__ __launch_bounds__(256) void prep_kernel(
    const float* __restrict__ Wih0, const float* __restrict__ Wih1,
    const float* __restrict__ bih0, const float* __restrict__ bhh0,
    const float* __restrict__ bih1, const float* __restrict__ bhh1,
    ushort* __restrict__ W0p, unsigned char* __restrict__ W1p8,
    float* __restrict__ b0p, float* __restrict__ b1p,
    unsigned int* __restrict__ done0)
{
  const int stride = gridDim.x * blockDim.x;
  const int gid = blockIdx.x * blockDim.x + threadIdx.x;
  // W0p[j][k] = Wih0[(j&3)*256 + (j>>2)][k]   (j = hid*4 + gate) bf16
  for (int i = gid; i < 1024 * 128; i += stride) {
    int j = i >> 7, k = i & 127;
    int p = ((j & 3) << 8) | (j >> 2);
    W0p[i] = f2bf(Wih0[p * 128 + k]);
  }
  // W1p8: RAW layout (row = gate*256+hid), fp8 e4m3 x64 (consumer chunk GEMM, R8-proven)
  for (int i = gid; i < 131072; i += stride) {
    int q = __builtin_amdgcn_cvt_pk_fp8_f32(Wih1[2 * i] * 64.f, Wih1[2 * i + 1] * 64.f, 0, false);
    ((ushort*)W1p8)[i] = (ushort)(q & 0xFFFF);
  }
  for (int i = gid; i < 1024; i += stride) {
    int p = ((i & 3) << 8) | (i >> 2);
    b0p[i] = bih0[p] + bhh0[p];   // gate-interleaved (producer xp0 epilogue)
    b1p[i] = bih1[p] + bhh1[p];   // gate-interleaved (consumer epilogue)
  }
  for (int i = gid; i < 128; i += stride) done0[i] = 0;  // reset chunk flags each launch
}

// ---------------- mega: layer-0 producer (WG 0-127) || layer-1 consumer (WG 128-255) ----------------
// Producer computes its own xp0 chunk in-kernel (emb gather + bf16 MFMA, bit-identical to
// the old gemm_xp path), runs 16 recurrent steps, then publishes the chunk's h0 (buffered
// in LDS) as ONE contiguous burst of u64 agent-scope atomic stores. Consumer = R13-proven.
__global__ __launch_bounds__(1024) void mega_scan(
    const int* __restrict__ x, const float* __restrict__ emb,
    const ushort* __restrict__ W0p, const float* __restrict__ b0p,
    const float* __restrict__ Whh0, const float* __restrict__ Whh1,
    const unsigned char* __restrict__ W1p8, const float* __restrict__ b1p,
    u64* __restrict__ hs64, unsigned int* __restrict__ done0,
    const float* __restrict__ fcw, const float* __restrict__ fcb,
    float* __restrict__ out)
{
  __shared__ __align__(16) unsigned char smem[42896];
  ushort* xpcu = (ushort*)smem;                 // [16][1024] bf16 xp chunk (both roles)
  unsigned char* h0l = smem + 32768;            // [16][272] emb-bf16 rows (prod) / fp8 h0 rows (cons)
  unsigned char* h0pub = smem + 37120;          // [16][256] fp8 h0 publish buffer (producer)
  unsigned char* hbb = smem + 41216;            // [2][320]  h ping-pong fp8
  float* hf = (float*)(smem + 41856);           // [260]     final h f32

  const int tid = threadIdx.x;
  const int l = tid & 63, w = tid >> 6;
  const int lr = l & 15, lg = l >> 4;
  const bool is0 = blockIdx.x < 128;
  const int b = is0 ? blockIdx.x : (blockIdx.x - 128);
  const float* Whh = is0 ? Whh0 : Whh1;
  const int hcol = 16 * w + lr;

  // W_hh fragments (fp8 x64): gate s, k-chunk kc; B col = 256*s + hcol, k = kc*128 + lg*32 + j
  i32x8 wf[4][2];
#pragma unroll
  for (int s = 0; s < 4; ++s) {
    const int n = 256 * s + hcol;
#pragma unroll
    for (int kc = 0; kc < 2; ++kc) {
      i32x8 r;
#pragma unroll
      for (int d = 0; d < 8; ++d) {
        const f32x4 v = *(const f32x4*)(Whh + (size_t)n * 256 + kc * 128 + lg * 32 + d * 4);
        int q = __builtin_amdgcn_cvt_pk_fp8_f32(v[0] * 64.f, v[1] * 64.f, 0, false);
        q = __builtin_amdgcn_cvt_pk_fp8_f32(v[2] * 64.f, v[3] * 64.f, q, true);
        r[d] = q;
      }
      wf[s][kc] = r;
    }
  }

  if (tid < 320) hbb[tid] = 0;  // h(-1) = 0 (buffer 0)
  float cc = 0.f;

  if (is0) {
    // ================= layer 0 producer =================
    // xp0 epilogue bias (j = 64w + nt*16 + lr), constant per lane
    float bias0n[4];
#pragma unroll
    for (int nt = 0; nt < 4; ++nt) bias0n[nt] = b0p[64 * w + nt * 16 + lr];
    __syncthreads();
    for (int c = 0; c < 32; ++c) {
      // --- emb gather: wave w stages timestep w's emb row as bf16 into h0l ---
      {
        const int rowidx = x[b * 512 + c * 16 + w];
        const float2 ev = *(const float2*)(emb + (size_t)rowidx * 128 + l * 2);
        const uint pk = (uint)f2bf(ev.x) | ((uint)f2bf(ev.y) << 16);
        *(uint*)(h0l + w * 272 + l * 4) = pk;
      }
      __syncthreads();
      // --- chunk xp0 GEMM: M=16 ts, N=64 cols/wave, K=128 bf16 (gemm_xp-identical maps) ---
      {
        s16x8 av[4];
#pragma unroll
        for (int ks = 0; ks < 4; ++ks)
          av[ks] = *(const s16x8*)(h0l + lr * 272 + ks * 64 + lg * 16);
        f32x4 ga0 = (f32x4)0.f, ga1 = (f32x4)0.f, ga2 = (f32x4)0.f, ga3 = (f32x4)0.f;
#pragma unroll
        for (int ks = 0; ks < 4; ++ks) {
          const s16x8 bv0 = *(const s16x8*)(W0p + (size_t)(64 * w + lr) * 128 + ks * 32 + lg * 8);
          const s16x8 bv1 = *(const s16x8*)(W0p + (size_t)(64 * w + 16 + lr) * 128 + ks * 32 + lg * 8);
          const s16x8 bv2 = *(const s16x8*)(W0p + (size_t)(64 * w + 32 + lr) * 128 + ks * 32 + lg * 8);
          const s16x8 bv3 = *(const s16x8*)(W0p + (size_t)(64 * w + 48 + lr) * 128 + ks * 32 + lg * 8);
          ga0 = __builtin_amdgcn_mfma_f32_16x16x32_bf16(av[ks], bv0, ga0, 0, 0, 0);
          ga1 = __builtin_amdgcn_mfma_f32_16x16x32_bf16(av[ks], bv1, ga1, 0, 0, 0);
          ga2 = __builtin_amdgcn_mfma_f32_16x16x32_bf16(av[ks], bv2, ga2, 0, 0, 0);
          ga3 = __builtin_amdgcn_mfma_f32_16x16x32_bf16(av[ks], bv3, ga3, 0, 0, 0);
        }
        // C: row = 4*lg + i (timestep), col j = 64w + nt*16 + lr (gate-interleaved layout)
#pragma unroll
        for (int i = 0; i < 4; ++i) {
          const int row = 4 * lg + i;
          xpcu[row * 1024 + 64 * w + lr]      = f2bf(ga0[i] + bias0n[0]);
          xpcu[row * 1024 + 64 * w + 16 + lr] = f2bf(ga1[i] + bias0n[1]);
          xpcu[row * 1024 + 64 * w + 32 + lr] = f2bf(ga2[i] + bias0n[2]);
          xpcu[row * 1024 + 64 * w + 48 + lr] = f2bf(ga3[i] + bias0n[3]);
        }
      }
      __syncthreads();
      // --- 16 recurrent steps (R7-verified structure; publish buffered to LDS) ---
      for (int ts = 0; ts < 16; ++ts) {
        const unsigned char* hr = hbb + ((ts & 1) * 320);
        unsigned char* hw = hbb + (((ts & 1) ^ 1) * 320);
        i32x8 af[2];
#pragma unroll
        for (int kc = 0; kc < 2; ++kc) {
          const uint4* p = (const uint4*)(hr + kc * 128 + lg * 32);
          uint4 lo = p[0], hi = p[1];
          i32x8 a;
          a[0] = lo.x; a[1] = lo.y; a[2] = lo.z; a[3] = lo.w;
          a[4] = hi.x; a[5] = hi.y; a[6] = hi.z; a[7] = hi.w;
          af[kc] = a;
        }
        f32x4 acc0 = (f32x4)0.f, acc1 = (f32x4)0.f, acc2 = (f32x4)0.f, acc3 = (f32x4)0.f;
#pragma unroll
        for (int kc = 0; kc < 2; ++kc) {
          acc0 = __builtin_amdgcn_mfma_scale_f32_16x16x128_f8f6f4(af[kc], wf[0][kc], acc0, 0, 0, 0, SCALE_ONE, 0, SCALE_ONE);
          acc1 = __builtin_amdgcn_mfma_scale_f32_16x16x128_f8f6f4(af[kc], wf[1][kc], acc1, 0, 0, 0, SCALE_ONE, 0, SCALE_ONE);
          acc2 = __builtin_amdgcn_mfma_scale_f32_16x16x128_f8f6f4(af[kc], wf[2][kc], acc2, 0, 0, 0, SCALE_ONE, 0, SCALE_ONE);
          acc3 = __builtin_amdgcn_mfma_scale_f32_16x16x128_f8f6f4(af[kc], wf[3][kc], acc3, 0, 0, 0, SCALE_ONE, 0, SCALE_ONE);
        }
        const uint2 xpv = *(const uint2*)(xpcu + ts * 1024 + (hcol << 2));
        const uint word = (lg & 2) ? xpv.y : xpv.x;
        const uint h16 = (lg & 1) ? (word >> 16) : (word & 0xFFFFu);
        union { uint32_t u; float f; } xf; xf.u = h16 << 16;
        const float accsel = (lg & 2) ? ((lg & 1) ? acc3[0] : acc2[0])
                                      : ((lg & 1) ? acc1[0] : acc0[0]);
        const float p = accsel * INV_SCALE + xf.f;
        const float kk2 = (lg == 2) ? (2.f * LOG2E) : LOG2E;
        const float mm = (lg == 2) ? 2.f : 1.f;
        const float ex = __builtin_amdgcn_exp2f(kk2 * p);
        const float v = 1.f - mm * __builtin_amdgcn_rcpf(ex + 1.f);
        const float sf = __shfl(v, lr + 16);
        const float tg = __shfl(v, lr + 32);
        const float so = __shfl(v, lr + 48);
        cc = sf * cc + v * tg;
        const float e2 = __builtin_amdgcn_exp2f(2.f * LOG2E * cc);
        const float th = 1.f - 2.f * __builtin_amdgcn_rcpf(e2 + 1.f);
        const float h = so * th;
        if (lg == 0) {
          int q = __builtin_amdgcn_cvt_pk_fp8_f32(h * 16.f, h * 16.f, 0, false);
          hw[hcol] = (unsigned char)(q & 0xFF);
          h0pub[ts * 256 + hcol] = (unsigned char)(q & 0xFF);
        }
        __syncthreads();
      }
      // --- burst publish: 512 contiguous u64 agent-scope stores (coalesced) ---
      if (tid < 512) {
        const int r = tid >> 5, kq = tid & 31;
        const u64 v = *(const u64*)(h0pub + r * 256 + (kq << 3));
        __hip_atomic_store(hs64 + ((size_t)b * 32 + c) * 512 + r * 32 + kq, v,
                           __ATOMIC_RELAXED, __HIP_MEMORY_SCOPE_AGENT);
      }
      __syncthreads();  // per-wave vmcnt drain: publish complete before flag
      if (tid == 0)
        __hip_atomic_store(done0 + b, (unsigned)(c + 1),
                           __ATOMIC_RELAXED, __HIP_MEMORY_SCOPE_AGENT);
    }
  } else {
    // ================= layer 1 consumer (R13-proven; contiguous hs64 blocks) =================
    const f32x4 bias = *(const f32x4*)(b1p + (hcol << 2));
    __syncthreads();
    for (int c = 0; c < 32; ++c) {
      if (tid == 0) {
        while (__hip_atomic_load(done0 + b, __ATOMIC_RELAXED, __HIP_MEMORY_SCOPE_AGENT)
               < (unsigned)(c + 1))
          __builtin_amdgcn_s_sleep(2);
      }
      __syncthreads();
      // stage 16x256 fp8 h0 chunk -> LDS rows (pad 272), contiguous u64 atomic loads
      if (tid < 512) {
        const int r = tid >> 5, kq = tid & 31;
        const u64 v = __hip_atomic_load(
            hs64 + ((size_t)b * 32 + c) * 512 + r * 32 + kq,
            __ATOMIC_RELAXED, __HIP_MEMORY_SCOPE_AGENT);
        *(u64*)(h0l + r * 272 + (kq << 3)) = v;
      }
      __syncthreads();
      // chunk GEMM: A rows = 16 timesteps (lane lr), B = W_ih1 fp8 from L2
      f32x4 ga0 = (f32x4)0.f, ga1 = (f32x4)0.f, ga2 = (f32x4)0.f, ga3 = (f32x4)0.f;
#pragma unroll
      for (int kc = 0; kc < 2; ++kc) {
        const uint4* ap = (const uint4*)(h0l + lr * 272 + (kc << 7) + (lg << 5));
        uint4 alo = ap[0], ahi = ap[1];
        i32x8 a;
        a[0] = alo.x; a[1] = alo.y; a[2] = alo.z; a[3] = alo.w;
        a[4] = ahi.x; a[5] = ahi.y; a[6] = ahi.z; a[7] = ahi.w;
        const unsigned char* wb = W1p8 + (size_t)hcol * 256 + (kc << 7) + (lg << 5);
#pragma unroll
        for (int g = 0; g < 4; ++g) {
          const uint4* bp = (const uint4*)(wb + (size_t)g * 65536);
          uint4 blo = bp[0], bhi = bp[1];
          i32x8 bv;
          bv[0] = blo.x; bv[1] = blo.y; bv[2] = blo.z; bv[3] = blo.w;
          bv[4] = bhi.x; bv[5] = bhi.y; bv[6] = bhi.z; bv[7] = bhi.w;
          if (g == 0) ga0 = __builtin_amdgcn_mfma_scale_f32_16x16x128_f8f6f4(a, bv, ga0, 0, 0, 0, SCALE_ONE, 0, SCALE_ONE);
          if (g == 1) ga1 = __builtin_amdgcn_mfma_scale_f32_16x16x128_f8f6f4(a, bv, ga1, 0, 0, 0, SCALE_ONE, 0, SCALE_ONE);
          if (g == 2) ga2 = __builtin_amdgcn_mfma_scale_f32_16x16x128_f8f6f4(a, bv, ga2, 0, 0, 0, SCALE_ONE, 0, SCALE_ONE);
          if (g == 3) ga3 = __builtin_amdgcn_mfma_scale_f32_16x16x128_f8f6f4(a, bv, ga3, 0, 0, 0, SCALE_ONE, 0, SCALE_ONE);
        }
      }
      // xp chunk -> LDS bf16, bias folded; C row = 4*lg + i (timestep), gate-interleaved cols
#pragma unroll
      for (int i = 0; i < 4; ++i) {
        const int row = (lg << 2) + i;
        union { uint2 u; ushort s[4]; } pk;
        pk.s[0] = f2bf(ga0[i] * INV_SCALE + bias[0]);
        pk.s[1] = f2bf(ga1[i] * INV_SCALE + bias[1]);
        pk.s[2] = f2bf(ga2[i] * INV_SCALE + bias[2]);
        pk.s[3] = f2bf(ga3[i] * INV_SCALE + bias[3]);
        *(uint2*)(xpcu + row * 1024 + (hcol << 2)) = pk.u;
      }
      __syncthreads();
      // 16 recurrent steps (R7-verified structure, xp from LDS gate-interleaved)
      for (int ts = 0; ts < 16; ++ts) {
        const int t = (c << 4) + ts;
        const unsigned char* hr = hbb + ((t & 1) * 320);
        unsigned char* hw = hbb + (((t & 1) ^ 1) * 320);
        i32x8 af[2];
#pragma unroll
        for (int kc = 0; kc < 2; ++kc) {
          const uint4* p = (const uint4*)(hr + kc * 128 + lg * 32);
          uint4 lo = p[0], hi = p[1];
          i32x8 a;
          a[0] = lo.x; a[1] = lo.y; a[2] = lo.z; a[3] = lo.w;
          a[4] = hi.x; a[5] = hi.y; a[6] = hi.z; a[7] = hi.w;
          af[kc] = a;
        }
        f32x4 acc0 = (f32x4)0.f, acc1 = (f32x4)0.f, acc2 = (f32x4)0.f, acc3 = (f32x4)0.f;
#pragma unroll
        for (int kc = 0; kc < 2; ++kc) {
          acc0 = __builtin_amdgcn_mfma_scale_f32_16x16x128_f8f6f4(af[kc], wf[0][kc], acc0, 0, 0, 0, SCALE_ONE, 0, SCALE_ONE);
          acc1 = __builtin_amdgcn_mfma_scale_f32_16x16x128_f8f6f4(af[kc], wf[1][kc], acc1, 0, 0, 0, SCALE_ONE, 0, SCALE_ONE);
          acc2 = __builtin_amdgcn_mfma_scale_f32_16x16x128_f8f6f4(af[kc], wf[2][kc], acc2, 0, 0, 0, SCALE_ONE, 0, SCALE_ONE);
          acc3 = __builtin_amdgcn_mfma_scale_f32_16x16x128_f8f6f4(af[kc], wf[3][kc], acc3, 0, 0, 0, SCALE_ONE, 0, SCALE_ONE);
        }
        const float xv = bf2f(xpcu[ts * 1024 + (hcol << 2) + lg]);
        const float accsel = (lg & 2) ? ((lg & 1) ? acc3[0] : acc2[0])
                                      : ((lg & 1) ? acc1[0] : acc0[0]);
        const float p = accsel * INV_SCALE + xv;
        const float kk2 = (lg == 2) ? (2.f * LOG2E) : LOG2E;
        const float mm = (lg == 2) ? 2.f : 1.f;
        const float ex = __builtin_amdgcn_exp2f(kk2 * p);
        const float v = 1.f - mm * __builtin_amdgcn_rcpf(ex + 1.f);
        const float sf = __shfl(v, lr + 16);
        const float tg = __shfl(v, lr + 32);
        const float so = __shfl(v, lr + 48);
        cc = sf * cc + v * tg;
        const float e2 = __builtin_amdgcn_exp2f(2.f * LOG2E * cc);
        const float th = 1.f - 2.f * __builtin_amdgcn_rcpf(e2 + 1.f);
        const float h = so * th;
        if (lg == 0) {
          int q = __builtin_amdgcn_cvt_pk_fp8_f32(h * 16.f, h * 16.f, 0, false);
          hw[hcol] = (unsigned char)(q & 0xFF);
          if (t == 511) hf[hcol] = h;
        }
        __syncthreads();
      }
    }
    // fc epilogue
    if (w == 0) {
      float s = 0.f;
#pragma unroll
      for (int j = 0; j < 4; ++j) {
        const int k = j * 64 + l;
        s += hf[k] * fcw[k];
      }
      s += __shfl_xor(s, 1);
      s += __shfl_xor(s, 2);
      s += __shfl_xor(s, 4);
      s += __shfl_xor(s, 8);
      s += __shfl_xor(s, 16);
      s += __shfl_xor(s, 32);
      if (l == 0) out[b] = sigm(s + fcb[0]);
    }
  }
}

// ---------------- launch ----------------
extern "C" void kernel_launch(void* const* d_in, const int* in_sizes, int n_in,
                              void* d_out, int out_size, void* d_ws, size_t ws_size,
                              hipStream_t stream)
{
  const int*   x    = (const int*)d_in[0];
  const float* emb  = (const float*)d_in[1];
  const float* fcw  = (const float*)d_in[2];
  const float* fcb  = (const float*)d_in[3];
  const float* Wih0 = (const float*)d_in[4];
  const float* Whh0 = (const float*)d_in[5];
  const float* bih0 = (const float*)d_in[6];
  const float* bhh0 = (const float*)d_in[7];
  const float* Wih1 = (const float*)d_in[8];
  const float* Whh1 = (const float*)d_in[9];
  const float* bih1 = (const float*)d_in[10];
  const float* bhh1 = (const float*)d_in[11];

  char* ws = (char*)d_ws;
  size_t off = 0;
  auto alloc = [&](size_t bytes) {
    void* p = ws + off;
    off = (off + bytes + 255) & ~(size_t)255;
    return p;
  };
  u64*           hs64   = (u64*)alloc(128ull * 32 * 512 * 8);
  ushort*        W0p    = (ushort*)alloc(1024ull * 128 * 2);
  unsigned char* W1p8   = (unsigned char*)alloc(1024ull * 256);
  float*         b0p    = (float*)alloc(1024 * 4);
  float*         b1p    = (float*)alloc(1024 * 4);
  unsigned int*  done0  = (unsigned int*)alloc(128 * 4);

  prep_kernel<<<256, 256, 0, stream>>>(Wih0, Wih1, bih0, bhh0, bih1, bhh1,
                                       W0p, W1p8, b0p, b1p, done0);
  mega_scan<<<256, 1024, 0, stream>>>(x, emb, W0p, b0p, Whh0, Whh1, W1p8, b1p,
                                      hs64, done0, fcw, fcb, (float*)d_out);
}